// Round 12
// baseline (162.222 us; speedup 1.0000x reference)
//
#include <hip/hip_runtime.h>
#include <hip/hip_bf16.h>

typedef unsigned short u16;
typedef unsigned int   u32;
typedef u32 __attribute__((address_space(1))) gas_u32;
typedef u32 __attribute__((address_space(3))) las_u32;
typedef __bf16 bf16x8 __attribute__((ext_vector_type(8)));
typedef float  f32x4  __attribute__((ext_vector_type(4)));

constexpr int BATCH = 4, SEQ = 4096, HID = 1024, NH = 16, DH = 64;
constexpr int M  = BATCH * SEQ;   // 16384 rows
constexpr int KD = HID;           // 1024 (K of all GEMMs)

__device__ __forceinline__ u16 f2bf(float f) {
  __hip_bfloat16 h = __float2bfloat16(f);
  u16 u; __builtin_memcpy(&u, &h, 2); return u;
}
__device__ __forceinline__ float bf2f(u16 u) {
  u32 x = ((u32)u) << 16; float f; __builtin_memcpy(&f, &x, 4); return f;
}

// ---------------- prep kernels ----------------

__global__ __launch_bounds__(256) void transpose_cast(const float* __restrict__ Wk,
                                                      const float* __restrict__ Wo,
                                                      u16* __restrict__ WkT,
                                                      u16* __restrict__ WoT) {
  __shared__ float tile[32][33];
  const float* src = blockIdx.z ? Wo : Wk;
  u16* dst = blockIdx.z ? WoT : WkT;
  int bx = blockIdx.x * 32, by = blockIdx.y * 32;
  int tx = threadIdx.x & 31, ty = threadIdx.x >> 5;
#pragma unroll
  for (int i = 0; i < 4; i++)
    tile[ty + i * 8][tx] = src[(size_t)(by + ty + i * 8) * HID + bx + tx];
  __syncthreads();
#pragma unroll
  for (int i = 0; i < 4; i++)
    dst[(size_t)(bx + ty + i * 8) * HID + by + tx] = f2bf(tile[tx][ty + i * 8]);
}

// WsT (64 x 1024 bf16): rows 0..15 colsum(Wq)/head, 16..31 colsum(Wv), 32..47 Wbeta, 48..63 zero
__global__ __launch_bounds__(256) void build_wsum(const float* __restrict__ Wq,
                                                  const float* __restrict__ Wv,
                                                  const float* __restrict__ Wbeta,
                                                  u16* __restrict__ WsT) {
  int tid = blockIdx.x * 256 + threadIdx.x;   // 65536
  int c = tid >> 10, kk = tid & 1023;
  float s = 0.f;
  if (c < 16)      { for (int d = 0; d < DH; d++) s += Wq[(size_t)kk * HID + c * DH + d]; }
  else if (c < 32) { for (int d = 0; d < DH; d++) s += Wv[(size_t)kk * HID + (c - 16) * DH + d]; }
  else if (c < 48) { s = Wbeta[(size_t)kk * NH + (c - 32)]; }
  WsT[(size_t)c * HID + kk] = f2bf(s);
}

// ======== fused cast + head-stat GEMM, K-SPLIT x4 (R10, verified) ========
__global__ __launch_bounds__(256) void skinny_part(
    const float* __restrict__ x, const u16* __restrict__ Bt,
    float* __restrict__ pq, float* __restrict__ pv, float* __restrict__ pb,
    u16* __restrict__ xb) {
  constexpr int BM = 64, BK = 64, KC = 256;
  __shared__ u16 As[BM * BK];
  __shared__ u16 Bs[64 * BK];
  const int tid = threadIdx.x, wave = tid >> 6, lane = tid & 63;
  const int bm = (int)blockIdx.x >> 2, kc = (int)blockIdx.x & 3;
  const int k0 = kc * KC;
  const int r16 = lane & 15, hi = lane >> 4;
  const int rsub = lane >> 3, csub = (lane & 7) * 8;
  f32x4 acc[4] = {};
  const float* Ab = x + (size_t)bm * BM * KD;
  u16* xbb = xb + (size_t)bm * BM * KD;

  for (int kt = k0; kt < k0 + KC; kt += BK) {
#pragma unroll
    for (int i = 0; i < 2; i++) {
      int slot = wave * 2 + i;
      const u16* g = Bt + (size_t)(slot * 8 + rsub) * KD + kt + csub;
      __builtin_amdgcn_global_load_lds((const gas_u32*)g, (las_u32*)(Bs + slot * 512), 16, 0, 0);
    }
#pragma unroll
    for (int p = 0; p < 2; p++) {
      const int row = p * 32 + (tid >> 3);
      const int c8 = (tid & 7) * 8;
      const float4 u0 = *(const float4*)(Ab + (size_t)row * KD + kt + c8);
      const float4 u1 = *(const float4*)(Ab + (size_t)row * KD + kt + c8 + 4);
      uint4 w;
      w.x = (u32)f2bf(u0.x) | ((u32)f2bf(u0.y) << 16);
      w.y = (u32)f2bf(u0.z) | ((u32)f2bf(u0.w) << 16);
      w.z = (u32)f2bf(u1.x) | ((u32)f2bf(u1.y) << 16);
      w.w = (u32)f2bf(u1.z) | ((u32)f2bf(u1.w) << 16);
      *(uint4*)(As + row * BK + c8) = w;
      *(uint4*)(xbb + (size_t)row * KD + kt + c8) = w;
    }
    __syncthreads();   // drains vmcnt (B DMA) + lgkmcnt (A ds_writes)
#pragma unroll
    for (int kk = 0; kk < 2; kk++) {
      bf16x8 af = *(const bf16x8*)(As + (wave * 16 + r16) * BK + kk * 32 + hi * 8);
#pragma unroll
      for (int fn = 0; fn < 4; fn++) {
        bf16x8 bfr = *(const bf16x8*)(Bs + (fn * 16 + r16) * BK + kk * 32 + hi * 8);
        acc[fn] = __builtin_amdgcn_mfma_f32_16x16x32_bf16(af, bfr, acc[fn], 0, 0, 0);
      }
    }
    __syncthreads();
  }

  const size_t kcoff = (size_t)kc * 64 * SEQ;
#pragma unroll
  for (int fn = 0; fn < 4; fn++) {
    const int col = fn * 16 + r16;
#pragma unroll
    for (int j = 0; j < 4; j++) {
      const int row = bm * BM + wave * 16 + hi * 4 + j;
      const int b = row >> 12, t = row & 4095;
      float v = acc[fn][j];
      if (col < 16)      pq[kcoff + ((size_t)(b * 16 + col)) * SEQ + t] = v;
      else if (col < 32) pv[kcoff + ((size_t)(b * 16 + col - 16)) * SEQ + t] = v;
      else if (col < 48) pb[kcoff + ((size_t)(b * 16 + col - 32)) * SEQ + t] = v;
    }
  }
}

// sum 4 K-chunk partials; bias+sigmoid on beta. idx = s*SEQ + t, s = b*16+head.
__global__ __launch_bounds__(256) void reduce_stats(
    const float* __restrict__ pq, const float* __restrict__ pv,
    const float* __restrict__ pb, const float* __restrict__ bbeta,
    float* __restrict__ sq, float* __restrict__ sv, float* __restrict__ sb) {
  constexpr int STR = 64 * SEQ;
  const int idx = blockIdx.x * 256 + threadIdx.x;   // 262144
  const int s = idx >> 12;
  float a = pq[idx] + pq[idx + STR] + pq[idx + 2 * STR] + pq[idx + 3 * STR];
  float b = pv[idx] + pv[idx + STR] + pv[idx + 2 * STR] + pv[idx + 3 * STR];
  float z = pb[idx] + pb[idx + STR] + pb[idx + 2 * STR] + pb[idx + 3 * STR] + bbeta[s & 15];
  sq[idx] = a;
  sv[idx] = b;
  sb[idx] = 1.f / (1.f + __expf(-z));
}

// ============ 128x128 4-wave phase-pipelined MFMA GEMM ============
// R12: same verified minimal-barrier schedule as R9/R11, tile halved to
// 128x128 so LDS = 2dbuf x (A+B) x 128x64 x 2B = 64 KiB -> 2 RESIDENT BLOCKS
// PER CU. R11 PMC showed flat dur with halved FETCH -> not fill-bound; the
// stall is barrier-convergence idle (all waves of the single block lockstep).
// Two independent blocks per SIMD overlap stalls (m114: MFMA+other-wave
// co-schedule is free).
// Schedule/ledger identical: prologue A0,A2,B0-3,A1,A3 -> vmcnt(2)+bar.
// ph0 {stage nA0,nA2; read aF0+bF; stage nB0,nB1; MFMA f01; vmcnt(4)+bar}
// ph1 {stage nB2,nB3; read aF1;   stage nA1,nA3; MFMA f23; vmcnt(2)+bar}
// Quarters are 32 rows (4 KB = 256 thr x 16 B). Last tile peeled (vmcnt(0)
// mid). T2 swizzle unchanged (0 conflicts). XCD-grouped mapping: grid 1024,
// bm=(bid&7)+8*(bid>>6), bn=(bid>>3)&7 -> per-XCD set = 8 A-panels (2 MB)
// + full B (2 MB) = 4 MB = L2.

__device__ __forceinline__ void stage_q128(const u16* __restrict__ Gk,
                                           int q, u16* lds_tile, int tid, int wave) {
  const int row = q * 32 + (tid >> 3);          // 32 rows per quarter
  const int s = tid & 7;                        // 16B col-group
  const u16* g = Gk + (size_t)row * KD + (size_t)((s ^ (row & 7)) << 3);
  u16* l = lds_tile + q * 2048 + wave * 512;    // wave-uniform LDS base, lanes +16B
  __builtin_amdgcn_global_load_lds((const gas_u32*)g, (las_u32*)l, 16, 0, 0);
}

__device__ __forceinline__ const bf16x8* lds_frag(const u16* lds_tile, int row, int cg) {
  return (const bf16x8*)(lds_tile + ((size_t)row << 6) + (size_t)((cg ^ (row & 7)) << 3));
}

// EPI 0: C = bf16(acc). EPI 2: C = bf16(xres + acc + bias).
template <int EPI>
__global__ __launch_bounds__(256) void gemm128(
    const u16* __restrict__ A, const u16* __restrict__ Bt, int N,
    u16* __restrict__ Cb, const u16* __restrict__ xres, const float* __restrict__ bias) {
  constexpr int BK = 64, NT = KD / BK;  // 16 K-tiles
  __shared__ u16 lds[2][2][8192];       // [buf][A=0/B=1][128*64] = 64 KiB
  const int tid = threadIdx.x, wave = tid >> 6, lane = tid & 63;
  const int wm = wave >> 1, wn = wave & 1;
  const int r16 = lane & 15, hi = lane >> 4;
  // XCD-grouped mapping (grid = 1024 = 128 bm x 8 bn):
  const int bid = (int)blockIdx.x;
  const int bm = (bid & 7) + 8 * (bid >> 6);
  const int bn = (bid >> 3) & 7;
  const u16* Abase = A + (size_t)bm * 128 * KD;
  const u16* Bbase = Bt + (size_t)bn * 128 * KD;

  f32x4 acc[4][4] = {};

  {
    u16* la = &lds[0][0][0]; u16* lb = &lds[0][1][0];
    stage_q128(Abase, 0, la, tid, wave);
    stage_q128(Abase, 2, la, tid, wave);
    stage_q128(Bbase, 0, lb, tid, wave);
    stage_q128(Bbase, 1, lb, tid, wave);
    stage_q128(Bbase, 2, lb, tid, wave);
    stage_q128(Bbase, 3, lb, tid, wave);
    stage_q128(Abase, 1, la, tid, wave);
    stage_q128(Abase, 3, la, tid, wave);
  }
  asm volatile("s_waitcnt vmcnt(2)" ::: "memory");
  __builtin_amdgcn_s_barrier();

  for (int kt = 0; kt < NT - 1; ++kt) {
    const int cur = kt & 1;
    const u16* la = &lds[cur][0][0];
    const u16* lb = &lds[cur][1][0];
    u16* na = &lds[cur ^ 1][0][0];
    u16* nb = &lds[cur ^ 1][1][0];
    const u16* An = Abase + (kt + 1) * BK;
    const u16* Bn = Bbase + (kt + 1) * BK;

    // ---- phase 0: rows wm*64+0..31 (f=0,1), both kk; read all bF ----
    stage_q128(An, 0, na, tid, wave);
    stage_q128(An, 2, na, tid, wave);
    bf16x8 bF[4][2], aF0[2][2];
#pragma unroll
    for (int kk = 0; kk < 2; ++kk) {
#pragma unroll
      for (int f = 0; f < 2; ++f)
        aF0[f][kk] = *lds_frag(la, wm * 64 + f * 16 + r16, kk * 4 + hi);
#pragma unroll
      for (int g = 0; g < 4; ++g)
        bF[g][kk] = *lds_frag(lb, wn * 64 + g * 16 + r16, kk * 4 + hi);
    }
    stage_q128(Bn, 0, nb, tid, wave);
    stage_q128(Bn, 1, nb, tid, wave);
    __builtin_amdgcn_s_setprio(1);
#pragma unroll
    for (int kk = 0; kk < 2; ++kk)
#pragma unroll
      for (int f = 0; f < 2; ++f)
#pragma unroll
        for (int g = 0; g < 4; ++g)
          acc[f][g] = __builtin_amdgcn_mfma_f32_16x16x32_bf16(
              aF0[f][kk], bF[g][kk], acc[f][g], 0, 0, 0);
    __builtin_amdgcn_s_setprio(0);
    asm volatile("s_waitcnt vmcnt(4)" ::: "memory");   // completes cA1,cA3
    __builtin_amdgcn_s_barrier();

    // ---- phase 1: rows wm*64+32..63 (f=2,3), reuse bF ----
    stage_q128(Bn, 2, nb, tid, wave);
    stage_q128(Bn, 3, nb, tid, wave);
    bf16x8 aF1[2][2];
#pragma unroll
    for (int kk = 0; kk < 2; ++kk)
#pragma unroll
      for (int f = 0; f < 2; ++f)
        aF1[f][kk] = *lds_frag(la, wm * 64 + 32 + f * 16 + r16, kk * 4 + hi);
    stage_q128(An, 1, na, tid, wave);
    stage_q128(An, 3, na, tid, wave);
    __builtin_amdgcn_s_setprio(1);
#pragma unroll
    for (int kk = 0; kk < 2; ++kk)
#pragma unroll
      for (int f = 0; f < 2; ++f)
#pragma unroll
        for (int g = 0; g < 4; ++g)
          acc[2 + f][g] = __builtin_amdgcn_mfma_f32_16x16x32_bf16(
              aF1[f][kk], bF[g][kk], acc[2 + f][g], 0, 0, 0);
    __builtin_amdgcn_s_setprio(0);
    asm volatile("s_waitcnt vmcnt(2)" ::: "memory");   // completes nA0,nA2,nB0-3
    __builtin_amdgcn_s_barrier();
  }

  // ---- last K-tile (peeled, no staging). Entering queue: [A1,A3]. ----
  {
    const u16* la = &lds[(NT - 1) & 1][0][0];
    const u16* lb = &lds[(NT - 1) & 1][1][0];
    bf16x8 bF[4][2], aF0[2][2];
#pragma unroll
    for (int kk = 0; kk < 2; ++kk) {
#pragma unroll
      for (int f = 0; f < 2; ++f)
        aF0[f][kk] = *lds_frag(la, wm * 64 + f * 16 + r16, kk * 4 + hi);
#pragma unroll
      for (int g = 0; g < 4; ++g)
        bF[g][kk] = *lds_frag(lb, wn * 64 + g * 16 + r16, kk * 4 + hi);
    }
    __builtin_amdgcn_s_setprio(1);
#pragma unroll
    for (int kk = 0; kk < 2; ++kk)
#pragma unroll
      for (int f = 0; f < 2; ++f)
#pragma unroll
        for (int g = 0; g < 4; ++g)
          acc[f][g] = __builtin_amdgcn_mfma_f32_16x16x32_bf16(
              aF0[f][kk], bF[g][kk], acc[f][g], 0, 0, 0);
    __builtin_amdgcn_s_setprio(0);
    asm volatile("s_waitcnt vmcnt(0)" ::: "memory");   // complete A1,A3
    __builtin_amdgcn_s_barrier();
    bf16x8 aF1[2][2];
#pragma unroll
    for (int kk = 0; kk < 2; ++kk)
#pragma unroll
      for (int f = 0; f < 2; ++f)
        aF1[f][kk] = *lds_frag(la, wm * 64 + 32 + f * 16 + r16, kk * 4 + hi);
    __builtin_amdgcn_s_setprio(1);
#pragma unroll
    for (int kk = 0; kk < 2; ++kk)
#pragma unroll
      for (int f = 0; f < 2; ++f)
#pragma unroll
        for (int g = 0; g < 4; ++g)
          acc[2 + f][g] = __builtin_amdgcn_mfma_f32_16x16x32_bf16(
              aF1[f][kk], bF[g][kk], acc[2 + f][g], 0, 0, 0);
    __builtin_amdgcn_s_setprio(0);
  }

  // epilogue
#pragma unroll
  for (int fm = 0; fm < 4; ++fm) {
#pragma unroll
    for (int fn = 0; fn < 4; ++fn) {
      const int col = bn * 128 + wn * 64 + fn * 16 + r16;
#pragma unroll
      for (int j = 0; j < 4; ++j) {
        const int row = bm * 128 + wm * 64 + fm * 16 + hi * 4 + j;
        float v = acc[fm][fn][j];
        if constexpr (EPI == 2) v += bf2f(xres[(size_t)row * N + col]) + bias[col];
        Cb[(size_t)row * N + col] = f2bf(v);
      }
    }
  }
}

// ---------------- chunked scan: r_t = b_t*r_{t-1} + k_t*vsum_t ----------------

__global__ __launch_bounds__(256) void scan_chunks(const u16* __restrict__ kbuf,
                                                   const float* __restrict__ sv_t,
                                                   const float* __restrict__ sb_t,
                                                   float* __restrict__ Pbuf,
                                                   float* __restrict__ Rloc) {
  const int wave = threadIdx.x >> 6, lane = threadIdx.x & 63;
  const int gid = blockIdx.x * 4 + wave;
  const int seq = gid >> 6, chunk = gid & 63;
  const int b = seq >> 4, h = seq & 15;
  const int t0 = chunk * 64;
  const float bet = sb_t[(size_t)seq * SEQ + t0 + lane];
  const float vs  = sv_t[(size_t)seq * SEQ + t0 + lane];
  const u16* kp = kbuf + ((size_t)(b * SEQ + t0)) * HID + h * DH + lane;
  float r = 0.f, P = 1.f;
#pragma unroll
  for (int tt = 0; tt < 64; tt += 8) {
    u16 kr[8];
#pragma unroll
    for (int j = 0; j < 8; j++) kr[j] = kp[(size_t)(tt + j) * HID];
#pragma unroll
    for (int j = 0; j < 8; j++) {
      float bt = __shfl(bet, tt + j);
      float vt = __shfl(vs, tt + j);
      r = fmaf(r, bt, bf2f(kr[j]) * vt);
      P *= bt;
    }
  }
  Rloc[(size_t)gid * 64 + lane] = r;
  if (lane == 0) Pbuf[gid] = P;
}

__global__ __launch_bounds__(64) void scan_prefix(const float* __restrict__ Pbuf,
                                                  const float* __restrict__ Rloc,
                                                  float* __restrict__ Rin) {
  const int seq = blockIdx.x, lane = threadIdx.x;
  const float* pp = Pbuf + seq * 64;
  const float* rl = Rloc + (size_t)seq * 64 * 64 + lane;
  float* ri = Rin + (size_t)seq * 64 * 64 + lane;
  float rin = 0.f;
#pragma unroll
  for (int c0 = 0; c0 < 64; c0 += 8) {
    float P[8], L[8];
#pragma unroll
    for (int j = 0; j < 8; j++) { P[j] = pp[c0 + j]; L[j] = rl[(size_t)(c0 + j) * 64]; }
#pragma unroll
    for (int j = 0; j < 8; j++) {
      ri[(size_t)(c0 + j) * 64] = rin;
      rin = fmaf(P[j], rin, L[j]);
    }
  }
}

__global__ __launch_bounds__(256) void scan_apply(const u16* __restrict__ kbuf,
                                                  const float* __restrict__ sq_t,
                                                  const float* __restrict__ sv_t,
                                                  const float* __restrict__ sb_t,
                                                  const float* __restrict__ Rin,
                                                  u16* __restrict__ obuf) {
  const int wave = threadIdx.x >> 6, lane = threadIdx.x & 63;
  const int gid = blockIdx.x * 4 + wave;
  const int seq = gid >> 6, chunk = gid & 63;
  const int b = seq >> 4, h = seq & 15;
  const int t0 = chunk * 64;
  const float bet = sb_t[(size_t)seq * SEQ + t0 + lane];
  const float vs  = sv_t[(size_t)seq * SEQ + t0 + lane];
  const float qs  = sq_t[(size_t)seq * SEQ + t0 + lane];
  const u16* kp = kbuf + ((size_t)(b * SEQ + t0)) * HID + h * DH + lane;
  u16* op = obuf + ((size_t)(b * SEQ + t0)) * HID + h * DH + lane;
  float r = Rin[(size_t)gid * 64 + lane];
#pragma unroll
  for (int tt = 0; tt < 64; tt += 8) {
    u16 kr[8];
#pragma unroll
    for (int j = 0; j < 8; j++) kr[j] = kp[(size_t)(tt + j) * HID];
#pragma unroll
    for (int j = 0; j < 8; j++) {
      float bt = __shfl(bet, tt + j);
      float vt = __shfl(vs, tt + j);
      float qt = __shfl(qs, tt + j);
      r = fmaf(r, bt, bf2f(kr[j]) * vt);
      op[(size_t)(tt + j) * HID] = f2bf(qt * r);
    }
  }
}

// ---------------- LayerNorm (row per block) ----------------
__global__ __launch_bounds__(256) void ln_kernel(const u16* __restrict__ y,
                                                 const float* __restrict__ g,
                                                 const float* __restrict__ bt,
                                                 float* __restrict__ out) {
  const int row = blockIdx.x;
  const u16* yr = y + (size_t)row * HID;
  const int t = threadIdx.x;
  ushort4 u = *(const ushort4*)(yr + t * 4);
  float v0 = bf2f(u.x), v1 = bf2f(u.y), v2 = bf2f(u.z), v3 = bf2f(u.w);
  float s  = v0 + v1 + v2 + v3;
  float ss = v0 * v0 + v1 * v1 + v2 * v2 + v3 * v3;
#pragma unroll
  for (int m = 1; m < 64; m <<= 1) { s += __shfl_xor(s, m); ss += __shfl_xor(ss, m); }
  __shared__ float red[8];
  const int wave = t >> 6, lane = t & 63;
  if (lane == 0) { red[wave] = s; red[4 + wave] = ss; }
  __syncthreads();
  float st  = red[0] + red[1] + red[2] + red[3];
  float sst = red[4] + red[5] + red[6] + red[7];
  float mu  = st * (1.f / 1024.f);
  float var = sst * (1.f / 1024.f) - mu * mu;
  float inv = rsqrtf(var + 1e-5f);
  const int c = t * 4;
  float4 o;
  o.x = g[c + 0] * ((v0 - mu) * inv) + bt[c + 0];
  o.y = g[c + 1] * ((v1 - mu) * inv) + bt[c + 1];
  o.z = g[c + 2] * ((v2 - mu) * inv) + bt[c + 2];
  o.w = g[c + 3] * ((v3 - mu) * inv) + bt[c + 3];
  *(float4*)(out + (size_t)row * HID + c) = o;
}

// ---------------- launch ----------------
extern "C" void kernel_launch(void* const* d_in, const int* in_sizes, int n_in,
                              void* d_out, int out_size, void* d_ws, size_t ws_size,
                              hipStream_t stream) {
  const float* x     = (const float*)d_in[0];
  const float* Wq    = (const float*)d_in[1];
  const float* Wk    = (const float*)d_in[2];
  const float* Wv    = (const float*)d_in[3];
  const float* Wbeta = (const float*)d_in[4];
  const float* bbeta = (const float*)d_in[5];
  const float* Wo    = (const float*)d_in[6];
  const float* b_o   = (const float*)d_in[7];
  const float* ln_g  = (const float*)d_in[8];
  const float* ln_b  = (const float*)d_in[9];
  float* out = (float*)d_out;

  char* ws = (char*)d_ws;
  size_t off = 0;
  auto alloc = [&](size_t bytes) {
    char* p = ws + off; off += (bytes + 255) & ~(size_t)255; return p;
  };
  u16* xb   = (u16*)alloc((size_t)M * HID * 2);   // x bf16 (residual for EPI2)
  u16* kbuf = (u16*)alloc((size_t)M * HID * 2);   // k; reused as y after scans
  u16* obuf = (u16*)alloc((size_t)M * HID * 2);   // o; FIRST 12 MB reused as stat partials
  u16* WkT  = (u16*)alloc((size_t)HID * HID * 2);
  u16* WoT  = (u16*)alloc((size_t)HID * HID * 2);
  u16* WsT  = (u16*)alloc((size_t)64 * HID * 2);
  float* sq_t = (float*)alloc((size_t)64 * SEQ * 4);
  float* sv_t = (float*)alloc((size_t)64 * SEQ * 4);
  float* sb_t = (float*)alloc((size_t)64 * SEQ * 4);
  float* Pbuf = (float*)alloc((size_t)4096 * 4);
  float* Rloc = (float*)alloc((size_t)4096 * 64 * 4);
  float* Rin  = (float*)alloc((size_t)4096 * 64 * 4);
  u16* ybuf = kbuf;  // kbuf dead (as k) after scan_apply

  // stat partials live in obuf (dead until scan_apply; reduce runs before it)
  float* pq = (float*)obuf;                       // 4 MB
  float* pv = pq + (size_t)4 * 64 * SEQ;          // 4 MB
  float* pb = pv + (size_t)4 * 64 * SEQ;          // 4 MB

  transpose_cast<<<dim3(32, 32, 2), 256, 0, stream>>>(Wk, Wo, WkT, WoT);
  build_wsum<<<256, 256, 0, stream>>>(Wq, Wv, Wbeta, WsT);

  // fused cast + head-stats, K-split x4 (1024 blocks = 4/CU)
  skinny_part<<<(M / 64) * 4, 256, 0, stream>>>(x, WsT, pq, pv, pb, xb);
  reduce_stats<<<(64 * SEQ) / 256, 256, 0, stream>>>(pq, pv, pb, bbeta, sq_t, sv_t, sb_t);

  // k = xb @ WkT^T  (128x128 pipelined, 1024 blocks = 2 resident/CU)
  gemm128<0><<<(M / 128) * (HID / 128), 256, 0, stream>>>(
      xb, WkT, HID, kbuf, nullptr, nullptr);

  scan_chunks<<<1024, 256, 0, stream>>>(kbuf, sv_t, sb_t, Pbuf, Rloc);
  scan_prefix<<<64, 64, 0, stream>>>(Pbuf, Rloc, Rin);
  scan_apply<<<1024, 256, 0, stream>>>(kbuf, sq_t, sv_t, sb_t, Rin, obuf);

  // y = bf16(xb + obuf @ WoT^T + b_o), written over kbuf (k dead)
  gemm128<2><<<(M / 128) * (HID / 128), 256, 0, stream>>>(
      obuf, WoT, HID, ybuf, xb, b_o);

  ln_kernel<<<M, 256, 0, stream>>>(ybuf, ln_g, ln_b, out);
}

// Round 13
// 150.371 us; speedup vs baseline: 1.0788x; 1.0788x over previous
//
#include <hip/hip_runtime.h>
#include <hip/hip_bf16.h>

typedef unsigned short u16;
typedef unsigned int   u32;
typedef u32 __attribute__((address_space(1))) gas_u32;
typedef u32 __attribute__((address_space(3))) las_u32;
typedef __bf16 bf16x8 __attribute__((ext_vector_type(8)));
typedef float  f32x4  __attribute__((ext_vector_type(4)));

constexpr int BATCH = 4, SEQ = 4096, HID = 1024, NH = 16, DH = 64;
constexpr int M  = BATCH * SEQ;   // 16384 rows
constexpr int KD = HID;           // 1024 (K of all GEMMs)

__device__ __forceinline__ u16 f2bf(float f) {
  __hip_bfloat16 h = __float2bfloat16(f);
  u16 u; __builtin_memcpy(&u, &h, 2); return u;
}
__device__ __forceinline__ float bf2f(u16 u) {
  u32 x = ((u32)u) << 16; float f; __builtin_memcpy(&f, &x, 4); return f;
}

// ---------------- prep kernels ----------------

__global__ __launch_bounds__(256) void transpose_cast(const float* __restrict__ Wk,
                                                      const float* __restrict__ Wo,
                                                      u16* __restrict__ WkT,
                                                      u16* __restrict__ WoT) {
  __shared__ float tile[32][33];
  const float* src = blockIdx.z ? Wo : Wk;
  u16* dst = blockIdx.z ? WoT : WkT;
  int bx = blockIdx.x * 32, by = blockIdx.y * 32;
  int tx = threadIdx.x & 31, ty = threadIdx.x >> 5;
#pragma unroll
  for (int i = 0; i < 4; i++)
    tile[ty + i * 8][tx] = src[(size_t)(by + ty + i * 8) * HID + bx + tx];
  __syncthreads();
#pragma unroll
  for (int i = 0; i < 4; i++)
    dst[(size_t)(bx + ty + i * 8) * HID + by + tx] = f2bf(tile[tx][ty + i * 8]);
}

// WsT (64 x 1024 bf16): rows 0..15 colsum(Wq)/head, 16..31 colsum(Wv), 32..47 Wbeta, 48..63 zero
__global__ __launch_bounds__(256) void build_wsum(const float* __restrict__ Wq,
                                                  const float* __restrict__ Wv,
                                                  const float* __restrict__ Wbeta,
                                                  u16* __restrict__ WsT) {
  int tid = blockIdx.x * 256 + threadIdx.x;   // 65536
  int c = tid >> 10, kk = tid & 1023;
  float s = 0.f;
  if (c < 16)      { for (int d = 0; d < DH; d++) s += Wq[(size_t)kk * HID + c * DH + d]; }
  else if (c < 32) { for (int d = 0; d < DH; d++) s += Wv[(size_t)kk * HID + (c - 16) * DH + d]; }
  else if (c < 48) { s = Wbeta[(size_t)kk * NH + (c - 32)]; }
  WsT[(size_t)c * HID + kk] = f2bf(s);
}

// ======== fused cast + head-stat GEMM, K-SPLIT x4 (R10, verified) ========
__global__ __launch_bounds__(256) void skinny_part(
    const float* __restrict__ x, const u16* __restrict__ Bt,
    float* __restrict__ pq, float* __restrict__ pv, float* __restrict__ pb,
    u16* __restrict__ xb) {
  constexpr int BM = 64, BK = 64, KC = 256;
  __shared__ u16 As[BM * BK];
  __shared__ u16 Bs[64 * BK];
  const int tid = threadIdx.x, wave = tid >> 6, lane = tid & 63;
  const int bm = (int)blockIdx.x >> 2, kc = (int)blockIdx.x & 3;
  const int k0 = kc * KC;
  const int r16 = lane & 15, hi = lane >> 4;
  const int rsub = lane >> 3, csub = (lane & 7) * 8;
  f32x4 acc[4] = {};
  const float* Ab = x + (size_t)bm * BM * KD;
  u16* xbb = xb + (size_t)bm * BM * KD;

  for (int kt = k0; kt < k0 + KC; kt += BK) {
#pragma unroll
    for (int i = 0; i < 2; i++) {
      int slot = wave * 2 + i;
      const u16* g = Bt + (size_t)(slot * 8 + rsub) * KD + kt + csub;
      __builtin_amdgcn_global_load_lds((const gas_u32*)g, (las_u32*)(Bs + slot * 512), 16, 0, 0);
    }
#pragma unroll
    for (int p = 0; p < 2; p++) {
      const int row = p * 32 + (tid >> 3);
      const int c8 = (tid & 7) * 8;
      const float4 u0 = *(const float4*)(Ab + (size_t)row * KD + kt + c8);
      const float4 u1 = *(const float4*)(Ab + (size_t)row * KD + kt + c8 + 4);
      uint4 w;
      w.x = (u32)f2bf(u0.x) | ((u32)f2bf(u0.y) << 16);
      w.y = (u32)f2bf(u0.z) | ((u32)f2bf(u0.w) << 16);
      w.z = (u32)f2bf(u1.x) | ((u32)f2bf(u1.y) << 16);
      w.w = (u32)f2bf(u1.z) | ((u32)f2bf(u1.w) << 16);
      *(uint4*)(As + row * BK + c8) = w;
      *(uint4*)(xbb + (size_t)row * KD + kt + c8) = w;
    }
    __syncthreads();   // drains vmcnt (B DMA) + lgkmcnt (A ds_writes)
#pragma unroll
    for (int kk = 0; kk < 2; kk++) {
      bf16x8 af = *(const bf16x8*)(As + (wave * 16 + r16) * BK + kk * 32 + hi * 8);
#pragma unroll
      for (int fn = 0; fn < 4; fn++) {
        bf16x8 bfr = *(const bf16x8*)(Bs + (fn * 16 + r16) * BK + kk * 32 + hi * 8);
        acc[fn] = __builtin_amdgcn_mfma_f32_16x16x32_bf16(af, bfr, acc[fn], 0, 0, 0);
      }
    }
    __syncthreads();
  }

  const size_t kcoff = (size_t)kc * 64 * SEQ;
#pragma unroll
  for (int fn = 0; fn < 4; fn++) {
    const int col = fn * 16 + r16;
#pragma unroll
    for (int j = 0; j < 4; j++) {
      const int row = bm * BM + wave * 16 + hi * 4 + j;
      const int b = row >> 12, t = row & 4095;
      float v = acc[fn][j];
      if (col < 16)      pq[kcoff + ((size_t)(b * 16 + col)) * SEQ + t] = v;
      else if (col < 32) pv[kcoff + ((size_t)(b * 16 + col - 16)) * SEQ + t] = v;
      else if (col < 48) pb[kcoff + ((size_t)(b * 16 + col - 32)) * SEQ + t] = v;
    }
  }
}

// ============ 256x256 8-wave phase-pipelined MFMA GEMM (R11, verified) ============
// Minimal-barrier schedule (R9): 2 barriers/tile, each directly after its
// counted vmcnt (wait -> barrier -> read). Ledger: enter [cA1,cA3]
// -> +nA0,nA2,nB0,nB1 -> vmcnt(4) -> +nB2,nB3,nA1,nA3 -> vmcnt(2).
// T2 swizzle (0 conflicts), setprio, last tile peeled. XCD-grouped mapping
// (R11): bm=(bid&7)+8*(bid>>5), bn=(bid>>3)&3 -> A filled once chip-wide.
// R12's 128^2/2-block variant REGRESSED (47.9 vs 43.0) -> reverted; GEMM
// structure closed at ~800 TF (sync/latency-bound plateau).

__device__ __forceinline__ void stage_quarter(const u16* __restrict__ Gk,
                                              int q, u16* lds_tile, int tid, int wave) {
  const int row = q * 64 + (tid >> 3);          // 64 rows per quarter
  const int s = tid & 7;                        // 16B col-group
  const u16* g = Gk + (size_t)row * KD + (size_t)((s ^ (row & 7)) << 3);
  u16* l = lds_tile + q * 4096 + wave * 512;    // wave-uniform LDS base, lanes +16B
  __builtin_amdgcn_global_load_lds((const gas_u32*)g, (las_u32*)l, 16, 0, 0);
}

__device__ __forceinline__ const bf16x8* lds_frag(const u16* lds_tile, int row, int cg) {
  return (const bf16x8*)(lds_tile + ((size_t)row << 6) + (size_t)((cg ^ (row & 7)) << 3));
}

// EPI 0: C = bf16(acc). EPI 2: C = bf16(xres + acc + bias).
template <int EPI>
__global__ __launch_bounds__(512) void gemm256(
    const u16* __restrict__ A, const u16* __restrict__ Bt, int N,
    u16* __restrict__ Cb, const u16* __restrict__ xres, const float* __restrict__ bias) {
  constexpr int BK = 64, NT = KD / BK;  // 16 K-tiles
  __shared__ u16 lds[2][2][16384];      // [buf][A=0/B=1][256*64]
  const int tid = threadIdx.x, wave = tid >> 6, lane = tid & 63;
  const int wm = wave >> 2, wn = wave & 3;
  const int r16 = lane & 15, hi = lane >> 4;
  const int bid = (int)blockIdx.x;
  const int bm = (bid & 7) + 8 * (bid >> 5);
  const int bn = (bid >> 3) & 3;
  const u16* Abase = A + (size_t)bm * 256 * KD;
  const u16* Bbase = Bt + (size_t)bn * 256 * KD;

  f32x4 acc[8][4] = {};

  {
    u16* la = &lds[0][0][0]; u16* lb = &lds[0][1][0];
    stage_quarter(Abase, 0, la, tid, wave);
    stage_quarter(Abase, 2, la, tid, wave);
    stage_quarter(Bbase, 0, lb, tid, wave);
    stage_quarter(Bbase, 1, lb, tid, wave);
    stage_quarter(Bbase, 2, lb, tid, wave);
    stage_quarter(Bbase, 3, lb, tid, wave);
    stage_quarter(Abase, 1, la, tid, wave);
    stage_quarter(Abase, 3, la, tid, wave);
  }
  asm volatile("s_waitcnt vmcnt(2)" ::: "memory");
  __builtin_amdgcn_s_barrier();

  for (int kt = 0; kt < NT - 1; ++kt) {
    const int cur = kt & 1;
    const u16* la = &lds[cur][0][0];
    const u16* lb = &lds[cur][1][0];
    u16* na = &lds[cur ^ 1][0][0];
    u16* nb = &lds[cur ^ 1][1][0];
    const u16* An = Abase + (kt + 1) * BK;
    const u16* Bn = Bbase + (kt + 1) * BK;

    // ---- first half-tile: mh=0 rows, both kk slices ----
    stage_quarter(An, 0, na, tid, wave);
    stage_quarter(An, 2, na, tid, wave);
    bf16x8 bF[4][2], aF0[4][2];
#pragma unroll
    for (int kk = 0; kk < 2; ++kk) {
#pragma unroll
      for (int f = 0; f < 4; ++f)
        aF0[f][kk] = *lds_frag(la, wm * 128 + f * 16 + r16, kk * 4 + hi);
#pragma unroll
      for (int g = 0; g < 4; ++g)
        bF[g][kk] = *lds_frag(lb, wn * 64 + g * 16 + r16, kk * 4 + hi);
    }
    stage_quarter(Bn, 0, nb, tid, wave);
    stage_quarter(Bn, 1, nb, tid, wave);
    __builtin_amdgcn_s_setprio(1);
#pragma unroll
    for (int kk = 0; kk < 2; ++kk)
#pragma unroll
      for (int f = 0; f < 4; ++f)
#pragma unroll
        for (int g = 0; g < 4; ++g)
          acc[f][g] = __builtin_amdgcn_mfma_f32_16x16x32_bf16(
              aF0[f][kk], bF[g][kk], acc[f][g], 0, 0, 0);
    __builtin_amdgcn_s_setprio(0);
    asm volatile("s_waitcnt vmcnt(4)" ::: "memory");   // completes cA1,cA3
    __builtin_amdgcn_s_barrier();

    // ---- second half-tile: mh=1 rows (A1/A3), reuse bF ----
    stage_quarter(Bn, 2, nb, tid, wave);
    stage_quarter(Bn, 3, nb, tid, wave);
    bf16x8 aF1[4][2];
#pragma unroll
    for (int kk = 0; kk < 2; ++kk)
#pragma unroll
      for (int f = 0; f < 4; ++f)
        aF1[f][kk] = *lds_frag(la, wm * 128 + 64 + f * 16 + r16, kk * 4 + hi);
    stage_quarter(An, 1, na, tid, wave);
    stage_quarter(An, 3, na, tid, wave);
    __builtin_amdgcn_s_setprio(1);
#pragma unroll
    for (int kk = 0; kk < 2; ++kk)
#pragma unroll
      for (int f = 0; f < 4; ++f)
#pragma unroll
        for (int g = 0; g < 4; ++g)
          acc[4 + f][g] = __builtin_amdgcn_mfma_f32_16x16x32_bf16(
              aF1[f][kk], bF[g][kk], acc[4 + f][g], 0, 0, 0);
    __builtin_amdgcn_s_setprio(0);
    asm volatile("s_waitcnt vmcnt(2)" ::: "memory");   // completes nA0,nA2,nB0-3
    __builtin_amdgcn_s_barrier();
  }

  // ---- last K-tile (peeled, no staging). Entering queue: [A1,A3]. ----
  {
    const u16* la = &lds[(NT - 1) & 1][0][0];
    const u16* lb = &lds[(NT - 1) & 1][1][0];
    bf16x8 bF[4][2], aF0[4][2];
#pragma unroll
    for (int kk = 0; kk < 2; ++kk) {
#pragma unroll
      for (int f = 0; f < 4; ++f)
        aF0[f][kk] = *lds_frag(la, wm * 128 + f * 16 + r16, kk * 4 + hi);
#pragma unroll
      for (int g = 0; g < 4; ++g)
        bF[g][kk] = *lds_frag(lb, wn * 64 + g * 16 + r16, kk * 4 + hi);
    }
    __builtin_amdgcn_s_setprio(1);
#pragma unroll
    for (int kk = 0; kk < 2; ++kk)
#pragma unroll
      for (int f = 0; f < 4; ++f)
#pragma unroll
        for (int g = 0; g < 4; ++g)
          acc[f][g] = __builtin_amdgcn_mfma_f32_16x16x32_bf16(
              aF0[f][kk], bF[g][kk], acc[f][g], 0, 0, 0);
    __builtin_amdgcn_s_setprio(0);
    asm volatile("s_waitcnt vmcnt(0)" ::: "memory");   // complete A1,A3
    __builtin_amdgcn_s_barrier();
    bf16x8 aF1[4][2];
#pragma unroll
    for (int kk = 0; kk < 2; ++kk)
#pragma unroll
      for (int f = 0; f < 4; ++f)
        aF1[f][kk] = *lds_frag(la, wm * 128 + 64 + f * 16 + r16, kk * 4 + hi);
    __builtin_amdgcn_s_setprio(1);
#pragma unroll
    for (int kk = 0; kk < 2; ++kk)
#pragma unroll
      for (int f = 0; f < 4; ++f)
#pragma unroll
        for (int g = 0; g < 4; ++g)
          acc[4 + f][g] = __builtin_amdgcn_mfma_f32_16x16x32_bf16(
              aF1[f][kk], bF[g][kk], acc[4 + f][g], 0, 0, 0);
    __builtin_amdgcn_s_setprio(0);
  }

  // epilogue
#pragma unroll
  for (int fm = 0; fm < 8; ++fm) {
#pragma unroll
    for (int fn = 0; fn < 4; ++fn) {
      const int col = bn * 256 + wn * 64 + fn * 16 + r16;
#pragma unroll
      for (int j = 0; j < 4; ++j) {
        const int row = bm * 256 + wm * 128 + fm * 16 + hi * 4 + j;
        float v = acc[fm][fn][j];
        if constexpr (EPI == 2) v += bf2f(xres[(size_t)row * N + col]) + bias[col];
        Cb[(size_t)row * N + col] = f2bf(v);
      }
    }
  }
}

// ---------------- chunked scan: r_t = b_t*r_{t-1} + k_t*vsum_t ----------------
// R13: head-stats consumed directly from K-chunk partials (4-sum + bias +
// sigmoid inline, same fp32 add order as the deleted reduce_stats kernel ->
// bit-identical). Saves a dispatch + its round-trip.

__global__ __launch_bounds__(256) void scan_chunks(const u16* __restrict__ kbuf,
                                                   const float* __restrict__ pv,
                                                   const float* __restrict__ pb,
                                                   const float* __restrict__ bbeta,
                                                   float* __restrict__ Pbuf,
                                                   float* __restrict__ Rloc) {
  constexpr size_t STR = (size_t)64 * SEQ;
  const int wave = threadIdx.x >> 6, lane = threadIdx.x & 63;
  const int gid = blockIdx.x * 4 + wave;
  const int seq = gid >> 6, chunk = gid & 63;
  const int b = seq >> 4, h = seq & 15;
  const int t0 = chunk * 64;
  const size_t idx = (size_t)seq * SEQ + t0 + lane;
  const float zb = pb[idx] + pb[idx + STR] + pb[idx + 2 * STR] + pb[idx + 3 * STR] + bbeta[h];
  const float bet = 1.f / (1.f + __expf(-zb));
  const float vs  = pv[idx] + pv[idx + STR] + pv[idx + 2 * STR] + pv[idx + 3 * STR];
  const u16* kp = kbuf + ((size_t)(b * SEQ + t0)) * HID + h * DH + lane;
  float r = 0.f, P = 1.f;
#pragma unroll
  for (int tt = 0; tt < 64; tt += 8) {
    u16 kr[8];
#pragma unroll
    for (int j = 0; j < 8; j++) kr[j] = kp[(size_t)(tt + j) * HID];
#pragma unroll
    for (int j = 0; j < 8; j++) {
      float bt = __shfl(bet, tt + j);
      float vt = __shfl(vs, tt + j);
      r = fmaf(r, bt, bf2f(kr[j]) * vt);
      P *= bt;
    }
  }
  Rloc[(size_t)gid * 64 + lane] = r;
  if (lane == 0) Pbuf[gid] = P;
}

__global__ __launch_bounds__(64) void scan_prefix(const float* __restrict__ Pbuf,
                                                  const float* __restrict__ Rloc,
                                                  float* __restrict__ Rin) {
  const int seq = blockIdx.x, lane = threadIdx.x;
  const float* pp = Pbuf + seq * 64;
  const float* rl = Rloc + (size_t)seq * 64 * 64 + lane;
  float* ri = Rin + (size_t)seq * 64 * 64 + lane;
  float rin = 0.f;
#pragma unroll
  for (int c0 = 0; c0 < 64; c0 += 8) {
    float P[8], L[8];
#pragma unroll
    for (int j = 0; j < 8; j++) { P[j] = pp[c0 + j]; L[j] = rl[(size_t)(c0 + j) * 64]; }
#pragma unroll
    for (int j = 0; j < 8; j++) {
      ri[(size_t)(c0 + j) * 64] = rin;
      rin = fmaf(P[j], rin, L[j]);
    }
  }
}

__global__ __launch_bounds__(256) void scan_apply(const u16* __restrict__ kbuf,
                                                  const float* __restrict__ pq,
                                                  const float* __restrict__ pv,
                                                  const float* __restrict__ pb,
                                                  const float* __restrict__ bbeta,
                                                  const float* __restrict__ Rin,
                                                  u16* __restrict__ obuf) {
  constexpr size_t STR = (size_t)64 * SEQ;
  const int wave = threadIdx.x >> 6, lane = threadIdx.x & 63;
  const int gid = blockIdx.x * 4 + wave;
  const int seq = gid >> 6, chunk = gid & 63;
  const int b = seq >> 4, h = seq & 15;
  const int t0 = chunk * 64;
  const size_t idx = (size_t)seq * SEQ + t0 + lane;
  const float zb = pb[idx] + pb[idx + STR] + pb[idx + 2 * STR] + pb[idx + 3 * STR] + bbeta[h];
  const float bet = 1.f / (1.f + __expf(-zb));
  const float vs  = pv[idx] + pv[idx + STR] + pv[idx + 2 * STR] + pv[idx + 3 * STR];
  const float qs  = pq[idx] + pq[idx + STR] + pq[idx + 2 * STR] + pq[idx + 3 * STR];
  const u16* kp = kbuf + ((size_t)(b * SEQ + t0)) * HID + h * DH + lane;
  u16* op = obuf + ((size_t)(b * SEQ + t0)) * HID + h * DH + lane;
  float r = Rin[(size_t)gid * 64 + lane];
#pragma unroll
  for (int tt = 0; tt < 64; tt += 8) {
    u16 kr[8];
#pragma unroll
    for (int j = 0; j < 8; j++) kr[j] = kp[(size_t)(tt + j) * HID];
#pragma unroll
    for (int j = 0; j < 8; j++) {
      float bt = __shfl(bet, tt + j);
      float vt = __shfl(vs, tt + j);
      float qt = __shfl(qs, tt + j);
      r = fmaf(r, bt, bf2f(kr[j]) * vt);
      op[(size_t)(tt + j) * HID] = f2bf(qt * r);
    }
  }
}

// ---------------- LayerNorm (row per block) ----------------
__global__ __launch_bounds__(256) void ln_kernel(const u16* __restrict__ y,
                                                 const float* __restrict__ g,
                                                 const float* __restrict__ bt,
                                                 float* __restrict__ out) {
  const int row = blockIdx.x;
  const u16* yr = y + (size_t)row * HID;
  const int t = threadIdx.x;
  ushort4 u = *(const ushort4*)(yr + t * 4);
  float v0 = bf2f(u.x), v1 = bf2f(u.y), v2 = bf2f(u.z), v3 = bf2f(u.w);
  float s  = v0 + v1 + v2 + v3;
  float ss = v0 * v0 + v1 * v1 + v2 * v2 + v3 * v3;
#pragma unroll
  for (int m = 1; m < 64; m <<= 1) { s += __shfl_xor(s, m); ss += __shfl_xor(ss, m); }
  __shared__ float red[8];
  const int wave = t >> 6, lane = t & 63;
  if (lane == 0) { red[wave] = s; red[4 + wave] = ss; }
  __syncthreads();
  float st  = red[0] + red[1] + red[2] + red[3];
  float sst = red[4] + red[5] + red[6] + red[7];
  float mu  = st * (1.f / 1024.f);
  float var = sst * (1.f / 1024.f) - mu * mu;
  float inv = rsqrtf(var + 1e-5f);
  const int c = t * 4;
  float4 o;
  o.x = g[c + 0] * ((v0 - mu) * inv) + bt[c + 0];
  o.y = g[c + 1] * ((v1 - mu) * inv) + bt[c + 1];
  o.z = g[c + 2] * ((v2 - mu) * inv) + bt[c + 2];
  o.w = g[c + 3] * ((v3 - mu) * inv) + bt[c + 3];
  *(float4*)(out + (size_t)row * HID + c) = o;
}

// ---------------- launch ----------------
extern "C" void kernel_launch(void* const* d_in, const int* in_sizes, int n_in,
                              void* d_out, int out_size, void* d_ws, size_t ws_size,
                              hipStream_t stream) {
  const float* x     = (const float*)d_in[0];
  const float* Wq    = (const float*)d_in[1];
  const float* Wk    = (const float*)d_in[2];
  const float* Wv    = (const float*)d_in[3];
  const float* Wbeta = (const float*)d_in[4];
  const float* bbeta = (const float*)d_in[5];
  const float* Wo    = (const float*)d_in[6];
  const float* b_o   = (const float*)d_in[7];
  const float* ln_g  = (const float*)d_in[8];
  const float* ln_b  = (const float*)d_in[9];
  float* out = (float*)d_out;

  char* ws = (char*)d_ws;
  size_t off = 0;
  auto alloc = [&](size_t bytes) {
    char* p = ws + off; off += (bytes + 255) & ~(size_t)255; return p;
  };
  u16* xb   = (u16*)alloc((size_t)M * HID * 2);   // x bf16 (residual for EPI2)
  u16* kbuf = (u16*)alloc((size_t)M * HID * 2);   // k; reused as y after scans
  u16* obuf = (u16*)alloc((size_t)M * HID * 2);
  u16* WkT  = (u16*)alloc((size_t)HID * HID * 2);
  u16* WoT  = (u16*)alloc((size_t)HID * HID * 2);
  u16* WsT  = (u16*)alloc((size_t)64 * HID * 2);
  float* pq = (float*)alloc((size_t)4 * 64 * SEQ * 4);   // K-chunk partials
  float* pv = (float*)alloc((size_t)4 * 64 * SEQ * 4);
  float* pb = (float*)alloc((size_t)4 * 64 * SEQ * 4);
  float* Pbuf = (float*)alloc((size_t)4096 * 4);
  float* Rloc = (float*)alloc((size_t)4096 * 64 * 4);
  float* Rin  = (float*)alloc((size_t)4096 * 64 * 4);
  u16* ybuf = kbuf;  // kbuf dead (as k) after scan_apply

  transpose_cast<<<dim3(32, 32, 2), 256, 0, stream>>>(Wk, Wo, WkT, WoT);
  build_wsum<<<256, 256, 0, stream>>>(Wq, Wv, Wbeta, WsT);

  // fused cast + head-stats, K-split x4 (1024 blocks = 4/CU)
  skinny_part<<<(M / 64) * 4, 256, 0, stream>>>(x, WsT, pq, pv, pb, xb);

  // k = xb @ WkT^T
  gemm256<0><<<(M / 256) * (HID / 256), 512, 0, stream>>>(
      xb, WkT, HID, kbuf, nullptr, nullptr);

  scan_chunks<<<1024, 256, 0, stream>>>(kbuf, pv, pb, bbeta, Pbuf, Rloc);
  scan_prefix<<<64, 64, 0, stream>>>(Pbuf, Rloc, Rin);
  scan_apply<<<1024, 256, 0, stream>>>(kbuf, pq, pv, pb, bbeta, Rin, obuf);

  // y = bf16(xb + obuf @ WoT^T + b_o), written over kbuf (k dead)
  gemm256<2><<<(M / 256) * (HID / 256), 512, 0, stream>>>(
      obuf, WoT, HID, ybuf, xb, b_o);

  ln_kernel<<<M, 256, 0, stream>>>(ybuf, ln_g, ln_b, out);
}